// Round 11
// baseline (328.079 us; speedup 1.0000x reference)
//
#include <hip/hip_runtime.h>
#include <hip/hip_bf16.h>
#include <stdint.h>

typedef __bf16 bf16;
typedef __attribute__((ext_vector_type(8))) __bf16 bf16x8;
typedef __attribute__((ext_vector_type(4))) __bf16 bf16x4;
typedef __attribute__((ext_vector_type(4))) float f32x4;

#define NSEQ 1028
#define CDIM 1024
#define NHEADS 16
#define HD 64
#define BHN 64          // B*H
#define NPAD 1088       // 17*64
#define M_REAL 4112     // B*NSEQ
#define MTILES 33       // 33 m-tiles of 128 (last starts at M_REAL-128, overlap)

static __device__ __forceinline__ void async_copy16(bf16* lds, const bf16* g) {
  __builtin_amdgcn_global_load_lds(
      (const __attribute__((address_space(1))) uint32_t*)g,
      (__attribute__((address_space(3))) uint32_t*)lds, 16, 0, 0);
}

// ---- fused fp32 -> bf16 cast for all three inputs (1 launch) ------------
__global__ __launch_bounds__(256) void cast3_kernel(
    const float* __restrict__ s0, bf16* __restrict__ d0, long n0,
    const float* __restrict__ s1, bf16* __restrict__ d1, long n1,
    const float* __restrict__ s2, bf16* __restrict__ d2, long n2) {
  long total = n0 + n1 + n2;   // all multiples of 4
  long t = (long)blockIdx.x * 256 + threadIdx.x;
  long stride = (long)gridDim.x * 256;
  for (long j = t * 4; j < total; j += stride * 4) {
    const float* s; bf16* d; long jj = j;
    if (jj < n0) { s = s0; d = d0; }
    else if (jj < n0 + n1) { s = s1; d = d1; jj -= n0; }
    else { s = s2; d = d2; jj -= n0 + n1; }
    float4 v = *(const float4*)(s + jj);
    bf16x4 o;
    o[0] = (bf16)v.x; o[1] = (bf16)v.y; o[2] = (bf16)v.z; o[3] = (bf16)v.w;
    *(bf16x4*)(d + jj) = o;
  }
}

// ---- bf16 MFMA GEMM, 128xBN tile, BK=32, A-only LDS, B direct from L2 ----
// C[m][n] = sum_k A[m][k] * Bm[n][k], K = CDIM = 1024, 32 K-steps.
// R11: B-fragments read DIRECTLY from global into registers -- weights are
// L2-pinned per-XCD by the R8 map, so these are ~L2-hit loads the compiler
// auto-waits (register dataflow). LDS = A-only 2x8KB = 16 KiB -> up to 8
// blocks/CU (R10 falsified depth>TLP: 4->3 blocks/CU regressed 24%).
// Counted vmcnt(2): b-frags (issued BEFORE stage) + stage(t) land, stage(t+1)
// stays in flight across the raw barrier. A-side keeps the R9 involution
// swizzle (0 conflicts). XCD weight-pinning map (R8). BN=128 (GEMM1) or
// BN=64 (GEMM2: 528 blocks = 2/CU, halves per-step MFMA vs fixed step cost).
// EPI==0: fused RMS-norm+rope epilogue -> q_bf/k_bf [bh][NPAD][64] + v_raw.
// EPI==1: fp32 C row-major (N = NSTRIP*8*BN columns).
template <int EPI, int NSTRIP, int BN>
__global__ __launch_bounds__(256, 6) void gemm_bf16_kernel(
    const bf16* __restrict__ A, const bf16* __restrict__ Bm,
    bf16* __restrict__ q_bf, bf16* __restrict__ k_bf, bf16* __restrict__ v_raw,
    float* __restrict__ outF,
    const float* __restrict__ cosb, const float* __restrict__ sinb,
    const float* __restrict__ nqw, const float* __restrict__ nkw) {
  constexpr int K = CDIM;
  constexpr int N = NSTRIP * 8 * BN;
  constexpr int HN = BN / 2;    // per-wave column span
  constexpr int NJ = BN / 32;   // b fragments / acc columns per wave
  __shared__ __attribute__((aligned(16))) bf16 As[2][128 * 32];
  const int tid = threadIdx.x;
  const int lane = tid & 63;
  const int wid = tid >> 6;
  const int wr = wid >> 1, wc = wid & 1;
  const int l15 = lane & 15, l4 = lane >> 4;

  // XCD weight-pinning work mapping (R8)
  const int xcd = blockIdx.x & 7;
  const int pos = blockIdx.x >> 3;          // 0 .. NSTRIP*MTILES-1
  const int nloc = pos % NSTRIP;
  const int mi = pos / NSTRIP;
  const int n0 = (xcd * NSTRIP + nloc) * BN;
  const int m0 = (mi < MTILES - 1) ? (mi << 7) : (M_REAL - 128);

  f32x4 acc[4][NJ] = {};

  // A staging: thread slot c holds physical 16B unit c; fetch logical
  // u = c ^ ((c>>3)&7) (involution). row = u>>2, chunk = u&3.
  size_t a_base[2];
#pragma unroll
  for (int s = 0; s < 2; s++) {
    int c = tid + s * 256;
    int u = c ^ ((c >> 3) & 7);
    a_base[s] = (size_t)(m0 + (u >> 2)) * K + ((u & 3) << 3);
  }

  // B direct-addressing: uniform per-wave row base + per-lane offset
  const size_t b_uni = (size_t)(n0 + wc * HN) * K;   // wave-uniform
  const int b_lane = l15 * K + l4 * 8;               // per-lane

#define STAGE(bufi, ktof)                                         \
  {                                                               \
    _Pragma("unroll")                                             \
    for (int s = 0; s < 2; s++)                                   \
      async_copy16(&As[bufi][(tid + s * 256) * 8], A + a_base[s] + (ktof)); \
  }

  const int nt = K >> 5;   // 32 K-steps
  STAGE(0, 0);             // 2 loads/thread in flight

  for (int t = 0; t < nt; ++t) {
    // b-fragments for tile t: direct global (L2-pinned strip), register dst
    bf16x8 bfr[NJ];
#pragma unroll
    for (int j = 0; j < NJ; j++)
      bfr[j] = *(const bf16x8*)(Bm + b_uni + (size_t)j * 16 * K + b_lane + (t << 5));

    if (t + 1 < nt) {
      STAGE((t + 1) & 1, (t + 1) << 5);
      asm volatile("s_waitcnt vmcnt(2)" ::: "memory");  // stage(t)+bfr landed
    } else {
      asm volatile("s_waitcnt vmcnt(0)" ::: "memory");
    }
    __builtin_amdgcn_s_barrier();  // raw: stage(t+1) stays in flight

    const int cur = t & 1;
    bf16x8 af[4];
#pragma unroll
    for (int i = 0; i < 4; i++) {
      int u = ((wr * 64 + i * 16 + l15) << 2) | l4;
      af[i] = *(const bf16x8*)&As[cur][(u ^ ((u >> 3) & 7)) << 3];
    }

#pragma unroll
    for (int i = 0; i < 4; i++)
#pragma unroll
      for (int j = 0; j < NJ; j++)
        acc[i][j] = __builtin_amdgcn_mfma_f32_16x16x32_bf16(af[i], bfr[j], acc[i][j], 0, 0, 0);

    asm volatile("s_waitcnt lgkmcnt(0)" ::: "memory");   // As[cur] reads done
    __builtin_amdgcn_s_barrier();
  }
#undef STAGE

  // epilogue: C/D layout col = lane&15, row = (lane>>4)*4 + reg
  if (EPI == 0) {
    // BN==128 here: wave spans 64 cols = one (matrix, head)
    const int d_base = n0 + wc * 64;
    const int tsel = d_base >> 10;
    const int hh = (d_base & 1023) >> 6;
    if (tsel == 2) {
#pragma unroll
      for (int i = 0; i < 4; i++)
#pragma unroll
        for (int r = 0; r < 4; r++) {
          int m = m0 + wr * 64 + i * 16 + l4 * 4 + r;   // always < M_REAL
          int b = m / NSEQ, n = m % NSEQ;
          size_t rb = ((size_t)(b * NHEADS + hh) * NSEQ + n) * HD;
#pragma unroll
          for (int j = 0; j < NJ; j++)
            v_raw[rb + j * 16 + l15] = (bf16)acc[i][j][r];
        }
    } else {
      const float* wn = (tsel == 0) ? nqw : nkw;
      bf16* dst = (tsel == 0) ? q_bf : k_bf;
      float wv[NJ];
#pragma unroll
      for (int j = 0; j < NJ; j++) wv[j] = wn[j * 16 + l15];
#pragma unroll
      for (int i = 0; i < 4; i++)
#pragma unroll
        for (int r = 0; r < 4; r++) {
          int m = m0 + wr * 64 + i * 16 + l4 * 4 + r;   // uniform across l15 group
          float ss = 0.0f;
#pragma unroll
          for (int j = 0; j < NJ; j++) { float x = acc[i][j][r]; ss += x * x; }
          ss += __shfl_xor(ss, 1);
          ss += __shfl_xor(ss, 2);
          ss += __shfl_xor(ss, 4);
          ss += __shfl_xor(ss, 8);
          float rms = rsqrtf(ss * (1.0f / HD) + 1e-6f);
          int b = m / NSEQ, n = m % NSEQ;
          float qn[NJ];
#pragma unroll
          for (int j = 0; j < NJ; j++) qn[j] = acc[i][j][r] * rms * wv[j];
          size_t rb = ((size_t)(b * NHEADS + hh) * NPAD + n) * HD;
#pragma unroll
          for (int j = 0; j < NJ; j++) {
            float c = cosb[n * HD + j * 16 + l15];
            float s = sinb[n * HD + j * 16 + l15];
            float rot = (j < 2) ? -qn[j + 2] : qn[j - 2];
            dst[rb + j * 16 + l15] = (bf16)(qn[j] * c + rot * s);
          }
        }
    }
  } else {
#pragma unroll
    for (int i = 0; i < 4; i++)
#pragma unroll
      for (int j = 0; j < NJ; j++) {
        int d = n0 + wc * HN + j * 16 + l15;
        int mrow = m0 + wr * 64 + i * 16 + l4 * 4;
#pragma unroll
        for (int r = 0; r < 4; r++) {
          int m = mrow + r;   // always < M_REAL (overlap tile double-writes)
          outF[(size_t)m * N + d] = acc[i][j][r];
        }
      }
  }
}

// ---- V transpose: v_raw [bh][n][64] -> vT [bh][64][NPAD] patch-aligned ----
__global__ __launch_bounds__(256) void v_transpose_kernel(const bf16* __restrict__ v_raw,
                                                          bf16* __restrict__ vT) {
  __shared__ bf16 tile[64][65];
  int bh = blockIdx.y, c = blockIdx.x;
  int tid = threadIdx.x;
#pragma unroll
  for (int jj = 0; jj < 16; jj++) {
    int idx = tid + jj * 256;
    int i = idx >> 6, e = idx & 63;
    int n = (c == 0) ? i : (64 * c - 60 + i);
    bool ok = (c == 0) ? (i < 4) : (n < NSEQ);
    tile[i][e] = ok ? v_raw[((size_t)bh * NSEQ + n) * HD + e] : (bf16)0.0f;
  }
  __syncthreads();
#pragma unroll
  for (int jj = 0; jj < 16; jj++) {
    int idx = tid + jj * 256;
    int e = idx >> 6, i = idx & 63;
    vT[((size_t)bh * HD + e) * NPAD + 64 * c + i] = tile[i][e];
  }
}

// ---------------- masked flash attention (balanced tiling) ---------------
__global__ __launch_bounds__(256) void attn_kernel(
    const bf16* __restrict__ Q, const bf16* __restrict__ Kb, const bf16* __restrict__ Vt,
    bf16* __restrict__ att, const int* __restrict__ winp) {
  __shared__ __attribute__((aligned(16))) bf16 P_s[4][16][72];
  __shared__ float o_s[4][4][64];
  __shared__ float ml_s[4][2][16];
  const int bh = blockIdx.y, qt = blockIdx.x;
  const int W = winp[0];
  const int tid = threadIdx.x, w = tid >> 6, lane = tid & 63;
  const int l15 = lane & 15, l4 = lane >> 4;
  const size_t qkbase = (size_t)bh * NPAD * HD;
  const size_t vtb = (size_t)bh * HD * NPAD;
  const bool is_spec = (qt == 16);

  const int qrow0 = is_spec ? 0 : (4 + qt * 64 + w * 16);
  bf16x8 aq0 = *(const bf16x8*)&Q[qkbase + (size_t)(qrow0 + l15) * HD + l4 * 8];
  bf16x8 aq1 = *(const bf16x8*)&Q[qkbase + (size_t)(qrow0 + l15) * HD + 32 + l4 * 8];

  float mrow[4], lrow[4];
  f32x4 o[4] = {};
#pragma unroll
  for (int r = 0; r < 4; r++) { mrow[r] = -1e30f; lrow[r] = 0.0f; }

  int p0, pstep, pmax, toff;
  if (is_spec) {
    p0 = w; pstep = 4; pmax = 16; toff = -1;
  } else {
    int ta = ((2 * qt - W + 64) >> 1) - 32;
    int tb = (2 * qt + 1 + W) >> 1;
    ta = ta < 0 ? 0 : ta;
    tb = tb > 15 ? 15 : tb;
    p0 = 0; pstep = 1; pmax = tb - ta + 1; toff = ta - 1;
  }

  for (int p = p0; p <= pmax; p += pstep) {
    const bool sp = (p == 0);
    const int tau = toff + p;
    const int krow0 = sp ? 0 : (4 + tau * 64);
    const int vcol0 = sp ? 0 : (64 + tau * 64);

    f32x4 sacc[4] = {};
#pragma unroll
    for (int kf = 0; kf < 4; kf++) {
      const bf16* kp = &Kb[qkbase + (size_t)(krow0 + kf * 16 + l15) * HD];
      bf16x8 b0 = *(const bf16x8*)(kp + l4 * 8);
      bf16x8 b1 = *(const bf16x8*)(kp + 32 + l4 * 8);
      sacc[kf] = __builtin_amdgcn_mfma_f32_16x16x32_bf16(aq0, b0, sacc[kf], 0, 0, 0);
      sacc[kf] = __builtin_amdgcn_mfma_f32_16x16x32_bf16(aq1, b1, sacc[kf], 0, 0, 0);
    }

    float pvv[4][4];
#pragma unroll
    for (int kf = 0; kf < 4; kf++)
#pragma unroll
      for (int r = 0; r < 4; r++) {
        float s = sacc[kf][r] * 0.125f;
        bool valid;
        if (sp) {
          valid = (kf == 0) && (l15 < 4);
        } else if (is_spec) {
          valid = true;
        } else {
          int p_k = tau * 64 + kf * 16 + l15;
          int p_q = qt * 64 + w * 16 + l4 * 4 + r;
          int dr = (p_q >> 5) - (p_k >> 5); dr = dr < 0 ? -dr : dr;
          int dc = (p_q & 31) - (p_k & 31); dc = dc < 0 ? -dc : dc;
          valid = (dr <= W) && (dc <= W);
        }
        pvv[kf][r] = valid ? s : -1e30f;
      }

#pragma unroll
    for (int r = 0; r < 4; r++) {
      float mx = fmaxf(fmaxf(pvv[0][r], pvv[1][r]), fmaxf(pvv[2][r], pvv[3][r]));
#pragma unroll
      for (int mm = 1; mm < 16; mm <<= 1) mx = fmaxf(mx, __shfl_xor(mx, mm));
      float mnew = fmaxf(mrow[r], mx);
      float scale = __expf(mrow[r] - mnew);
      float rs = 0.0f;
#pragma unroll
      for (int kf = 0; kf < 4; kf++) {
        float pp = __expf(pvv[kf][r] - mnew);
        pvv[kf][r] = pp;
        rs += pp;
      }
#pragma unroll
      for (int mm = 1; mm < 16; mm <<= 1) rs += __shfl_xor(rs, mm);
      lrow[r] = lrow[r] * scale + rs;
      mrow[r] = mnew;
#pragma unroll
      for (int f = 0; f < 4; f++) o[f][r] *= scale;
    }

#pragma unroll
    for (int kf = 0; kf < 4; kf++)
#pragma unroll
      for (int r = 0; r < 4; r++)
        P_s[w][l4 * 4 + r][kf * 16 + l15] = (bf16)pvv[kf][r];

    bf16x8 pa0 = *(const bf16x8*)&P_s[w][l15][l4 * 8];
    bf16x8 pa1 = *(const bf16x8*)&P_s[w][l15][32 + l4 * 8];
#pragma unroll
    for (int f = 0; f < 4; f++) {
      const bf16* vp = &Vt[vtb + (size_t)(f * 16 + l15) * NPAD + vcol0];
      bf16x8 v0 = *(const bf16x8*)(vp + l4 * 8);
      bf16x8 v1 = *(const bf16x8*)(vp + 32 + l4 * 8);
      o[f] = __builtin_amdgcn_mfma_f32_16x16x32_bf16(pa0, v0, o[f], 0, 0, 0);
      o[f] = __builtin_amdgcn_mfma_f32_16x16x32_bf16(pa1, v1, o[f], 0, 0, 0);
    }
  }

  const int b = bh >> 4, h = bh & 15;
  if (!is_spec) {
#pragma unroll
    for (int f = 0; f < 4; f++)
#pragma unroll
      for (int r = 0; r < 4; r++) {
        int n = qrow0 + l4 * 4 + r;
        att[((size_t)(b * NSEQ + n)) * CDIM + h * HD + f * 16 + l15] =
            (bf16)(o[f][r] / lrow[r]);
      }
  } else {
    if (l4 == 0) {
#pragma unroll
      for (int f = 0; f < 4; f++)
#pragma unroll
        for (int r = 0; r < 4; r++) o_s[w][r][f * 16 + l15] = o[f][r];
      if (l15 == 0)
#pragma unroll
        for (int r = 0; r < 4; r++) { ml_s[w][0][r] = mrow[r]; ml_s[w][1][r] = lrow[r]; }
    }
    __syncthreads();
    int row = tid >> 6, dim = tid & 63;
    float M = -1e30f;
#pragma unroll
    for (int ww = 0; ww < 4; ww++) M = fmaxf(M, ml_s[ww][0][row]);
    float L = 0.0f, val = 0.0f;
#pragma unroll
    for (int ww = 0; ww < 4; ww++) {
      float e = __expf(ml_s[ww][0][row] - M);
      L += e * ml_s[ww][1][row];
      val += e * o_s[ww][row][dim];
    }
    att[((size_t)(b * NSEQ + row)) * CDIM + h * HD + dim] = (bf16)(val / L);
  }
}

// ------------------------------------------------------------------------
extern "C" void kernel_launch(void* const* d_in, const int* in_sizes, int n_in,
                              void* d_out, int out_size, void* d_ws, size_t ws_size,
                              hipStream_t stream) {
  const float* hidden = (const float*)d_in[0];
  const float* cosb = (const float*)d_in[1];
  const float* sinb = (const float*)d_in[2];
  const float* qkv_w = (const float*)d_in[3];
  const float* out_w = (const float*)d_in[4];
  const float* norm_q_w = (const float*)d_in[5];
  const float* norm_k_w = (const float*)d_in[6];
  const int* win = (const int*)d_in[7];
  float* out = (float*)d_out;

  char* ws = (char*)d_ws;
  size_t off = 0;
  auto alloc = [&](size_t bytes) {
    char* p = ws + off;
    off += (bytes + 255) & ~(size_t)255;
    return p;
  };
  bf16* A_bf  = (bf16*)alloc((size_t)M_REAL * CDIM * 2);
  bf16* W1    = (bf16*)alloc((size_t)3 * CDIM * CDIM * 2);
  bf16* W2    = (bf16*)alloc((size_t)CDIM * CDIM * 2);
  bf16* v_raw = (bf16*)alloc((size_t)BHN * NSEQ * HD * 2);
  bf16* q_bf  = (bf16*)alloc((size_t)BHN * NPAD * HD * 2);
  bf16* k_bf  = (bf16*)alloc((size_t)BHN * NPAD * HD * 2);
  bf16* vT    = (bf16*)alloc((size_t)BHN * HD * NPAD * 2);
  bf16* att   = (bf16*)alloc((size_t)M_REAL * CDIM * 2);
  (void)ws_size; (void)in_sizes; (void)n_in; (void)out_size;

  cast3_kernel<<<2048, 256, 0, stream>>>(
      hidden, A_bf, (long)M_REAL * CDIM,
      qkv_w, W1, (long)3 * CDIM * CDIM,
      out_w, W2, (long)CDIM * CDIM);

  // GEMM1: 8 XCD x 3 n-strips x 33 m-tiles = 792 blocks, BN=128;
  // 0.75MB W1 strip/XCD stays L2-pinned, B read direct from L2.
  gemm_bf16_kernel<0, 3, 128><<<792, 256, 0, stream>>>(
      A_bf, W1, q_bf, k_bf, v_raw, nullptr, cosb, sinb, norm_q_w, norm_k_w);
  v_transpose_kernel<<<dim3(17, 64), 256, 0, stream>>>(v_raw, vT);
  attn_kernel<<<dim3(17, 64), 256, 0, stream>>>(q_bf, k_bf, vT, att, win);
  // GEMM2: 8 XCD x 2 n-strips x 33 m-tiles = 528 blocks, BN=64 (2 blocks/CU);
  // 0.25MB W2 strip/XCD L2-pinned.
  gemm_bf16_kernel<1, 2, 64><<<528, 256, 0, stream>>>(
      att, W2, nullptr, nullptr, nullptr, out, nullptr, nullptr, nullptr, nullptr);
}

// Round 12
// 127.842 us; speedup vs baseline: 2.5663x; 2.5663x over previous
//
#include <hip/hip_runtime.h>
#include <hip/hip_bf16.h>
#include <stdint.h>

typedef __bf16 bf16;
typedef __attribute__((ext_vector_type(8))) __bf16 bf16x8;
typedef __attribute__((ext_vector_type(4))) __bf16 bf16x4;
typedef __attribute__((ext_vector_type(4))) float f32x4;

#define NSEQ 1028
#define CDIM 1024
#define NHEADS 16
#define HD 64
#define BHN 64          // B*H
#define NPAD 1088       // 17*64
#define M_REAL 4112     // B*NSEQ
#define MTILES 33       // 33 m-tiles of 128 (last starts at M_REAL-128, overlap)

static __device__ __forceinline__ void async_copy16(bf16* lds, const bf16* g) {
  __builtin_amdgcn_global_load_lds(
      (const __attribute__((address_space(1))) uint32_t*)g,
      (__attribute__((address_space(3))) uint32_t*)lds, 16, 0, 0);
}

// ---- fused fp32 -> bf16 cast for all three inputs (1 launch) ------------
__global__ __launch_bounds__(256) void cast3_kernel(
    const float* __restrict__ s0, bf16* __restrict__ d0, long n0,
    const float* __restrict__ s1, bf16* __restrict__ d1, long n1,
    const float* __restrict__ s2, bf16* __restrict__ d2, long n2) {
  long total = n0 + n1 + n2;   // all multiples of 4
  long t = (long)blockIdx.x * 256 + threadIdx.x;
  long stride = (long)gridDim.x * 256;
  for (long j = t * 4; j < total; j += stride * 4) {
    const float* s; bf16* d; long jj = j;
    if (jj < n0) { s = s0; d = d0; }
    else if (jj < n0 + n1) { s = s1; d = d1; jj -= n0; }
    else { s = s2; d = d2; jj -= n0 + n1; }
    float4 v = *(const float4*)(s + jj);
    bf16x4 o;
    o[0] = (bf16)v.x; o[1] = (bf16)v.y; o[2] = (bf16)v.z; o[3] = (bf16)v.w;
    *(bf16x4*)(d + jj) = o;
  }
}

// ---- bf16 MFMA GEMM, 128m x BN tile, BK=32, dbuf, counted vmcnt ----------
// C[m][n] = sum_k A[m][k] * Bm[n][k], K = CDIM = 1024, 32 K-steps.
// R12 = R9 (best verified: 49.8us GEMM1, 0 conflicts, no spills) templated
// on BN: BN=128 is byte-identical R9 GEMM1; BN=64 halves the B tile so
// GEMM2 runs 528 blocks (2.06/CU) instead of 264 (1/CU, zero TLP).
// R11 lesson: never force occupancy via launch_bounds beyond VGPR budget
// (min-waves 6 -> 40 VGPR cap -> 466MB scratch spill, 6x regression).
// LDS unit involution (both sides, rule #21): phys = u ^ ((u>>3)&7);
// A tile 128x32 (512 units), B tile BNx32 (BN*4 units); per-16-lane frag
// phase hits each bank cluster exactly 2x (free, m136).
// Counted vmcnt(L), L = loads/thread/step = 2 + BN/64; raw barriers.
// XCD weight-pinning map (R8): B strip (NSTRIP*BN cols) L2-resident/XCD.
// EPI==0 (BN=128): fused RMS-norm+rope -> q_bf/k_bf [bh][NPAD][64] + v_raw.
// EPI==1: fp32 C row-major, N = NSTRIP*8*BN.
template <int EPI, int NSTRIP, int BN>
__global__ __launch_bounds__(256, 4) void gemm_bf16_kernel(
    const bf16* __restrict__ A, const bf16* __restrict__ Bm,
    bf16* __restrict__ q_bf, bf16* __restrict__ k_bf, bf16* __restrict__ v_raw,
    float* __restrict__ outF,
    const float* __restrict__ cosb, const float* __restrict__ sinb,
    const float* __restrict__ nqw, const float* __restrict__ nkw) {
  constexpr int K = CDIM;
  constexpr int N = NSTRIP * 8 * BN;
  constexpr int HN = BN / 2;        // per-wave column span
  constexpr int NJ = HN / 16;       // b fragments / acc cols per wave
  constexpr int BSLOTS = (BN * 4) / 256;  // B stage slots/thread (2 or 1)
  constexpr int LPS = 2 + BSLOTS;   // loads per thread per stage
  __shared__ __attribute__((aligned(16))) bf16 As[2][128 * 32];
  __shared__ __attribute__((aligned(16))) bf16 Bs[2][BN * 32];
  const int tid = threadIdx.x;
  const int lane = tid & 63;
  const int wid = tid >> 6;
  const int wr = wid >> 1, wc = wid & 1;
  const int l15 = lane & 15, l4 = lane >> 4;

  // XCD weight-pinning work mapping (R8)
  const int xcd = blockIdx.x & 7;
  const int pos = blockIdx.x >> 3;          // 0 .. NSTRIP*MTILES-1
  const int nloc = pos % NSTRIP;
  const int mi = pos / NSTRIP;
  const int n0 = (xcd * NSTRIP + nloc) * BN;
  const int m0 = (mi < MTILES - 1) ? (mi << 7) : (M_REAL - 128);

  f32x4 acc[4][NJ] = {};

  // staging sources: thread slot c holds physical unit c -> fetch logical
  // unit u = c ^ ((c>>3)&7) (involution). row = u>>2, chunk = u&3 (16B).
  size_t a_base[2], b_base[BSLOTS];
#pragma unroll
  for (int s = 0; s < 2; s++) {
    int c = tid + s * 256;
    int u = c ^ ((c >> 3) & 7);
    a_base[s] = (size_t)(m0 + (u >> 2)) * K + ((u & 3) << 3);
  }
#pragma unroll
  for (int s = 0; s < BSLOTS; s++) {
    int c = tid + s * 256;
    int u = c ^ ((c >> 3) & 7);
    b_base[s] = (size_t)(n0 + (u >> 2)) * K + ((u & 3) << 3);
  }

#define STAGE(bufi, ktof)                                                   \
  {                                                                         \
    _Pragma("unroll")                                                       \
    for (int s = 0; s < 2; s++)                                             \
      async_copy16(&As[bufi][(tid + s * 256) * 8], A + a_base[s] + (ktof)); \
    _Pragma("unroll")                                                       \
    for (int s = 0; s < BSLOTS; s++)                                        \
      async_copy16(&Bs[bufi][(tid + s * 256) * 8], Bm + b_base[s] + (ktof));\
  }

  const int nt = K >> 5;   // 32 K-steps
  STAGE(0, 0);             // LPS loads/thread in flight

  for (int t = 0; t < nt; ++t) {
    if (t + 1 < nt) {
      STAGE((t + 1) & 1, (t + 1) << 5);
      asm volatile("s_waitcnt vmcnt(%0)" :: "i"(LPS) : "memory");  // tile t landed
    } else {
      asm volatile("s_waitcnt vmcnt(0)" ::: "memory");
    }
    __builtin_amdgcn_s_barrier();  // raw: tile t+1's loads stay in flight

    const int cur = t & 1;
    bf16x8 af[4], bfr[NJ];
#pragma unroll
    for (int i = 0; i < 4; i++) {
      int u = ((wr * 64 + i * 16 + l15) << 2) | l4;
      af[i] = *(const bf16x8*)&As[cur][(u ^ ((u >> 3) & 7)) << 3];
    }
#pragma unroll
    for (int j = 0; j < NJ; j++) {
      int u = ((wc * HN + j * 16 + l15) << 2) | l4;
      bfr[j] = *(const bf16x8*)&Bs[cur][(u ^ ((u >> 3) & 7)) << 3];
    }

#pragma unroll
    for (int i = 0; i < 4; i++)
#pragma unroll
      for (int j = 0; j < NJ; j++)
        acc[i][j] = __builtin_amdgcn_mfma_f32_16x16x32_bf16(af[i], bfr[j], acc[i][j], 0, 0, 0);

    asm volatile("s_waitcnt lgkmcnt(0)" ::: "memory");   // buf[cur] reads done
    __builtin_amdgcn_s_barrier();
  }
#undef STAGE

  // epilogue: C/D layout col = lane&15, row = (lane>>4)*4 + reg
  if (EPI == 0) {
    // BN==128: wave spans 64 cols = one (matrix, head)
    const int d_base = n0 + wc * 64;
    const int tsel = d_base >> 10;
    const int hh = (d_base & 1023) >> 6;
    if (tsel == 2) {
#pragma unroll
      for (int i = 0; i < 4; i++)
#pragma unroll
        for (int r = 0; r < 4; r++) {
          int m = m0 + wr * 64 + i * 16 + l4 * 4 + r;   // always < M_REAL
          int b = m / NSEQ, n = m % NSEQ;
          size_t rb = ((size_t)(b * NHEADS + hh) * NSEQ + n) * HD;
#pragma unroll
          for (int j = 0; j < NJ; j++)
            v_raw[rb + j * 16 + l15] = (bf16)acc[i][j][r];
        }
    } else {
      const float* wn = (tsel == 0) ? nqw : nkw;
      bf16* dst = (tsel == 0) ? q_bf : k_bf;
      float wv[NJ];
#pragma unroll
      for (int j = 0; j < NJ; j++) wv[j] = wn[j * 16 + l15];
#pragma unroll
      for (int i = 0; i < 4; i++)
#pragma unroll
        for (int r = 0; r < 4; r++) {
          int m = m0 + wr * 64 + i * 16 + l4 * 4 + r;   // uniform across l15 group
          float ss = 0.0f;
#pragma unroll
          for (int j = 0; j < NJ; j++) { float x = acc[i][j][r]; ss += x * x; }
          ss += __shfl_xor(ss, 1);
          ss += __shfl_xor(ss, 2);
          ss += __shfl_xor(ss, 4);
          ss += __shfl_xor(ss, 8);
          float rms = rsqrtf(ss * (1.0f / HD) + 1e-6f);
          int b = m / NSEQ, n = m % NSEQ;
          float qn[NJ];
#pragma unroll
          for (int j = 0; j < NJ; j++) qn[j] = acc[i][j][r] * rms * wv[j];
          size_t rb = ((size_t)(b * NHEADS + hh) * NPAD + n) * HD;
#pragma unroll
          for (int j = 0; j < NJ; j++) {
            float c = cosb[n * HD + j * 16 + l15];
            float s = sinb[n * HD + j * 16 + l15];
            float rot = (j < 2) ? -qn[j + 2] : qn[j - 2];
            dst[rb + j * 16 + l15] = (bf16)(qn[j] * c + rot * s);
          }
        }
    }
  } else {
#pragma unroll
    for (int i = 0; i < 4; i++)
#pragma unroll
      for (int j = 0; j < NJ; j++) {
        int d = n0 + wc * HN + j * 16 + l15;
        int mrow = m0 + wr * 64 + i * 16 + l4 * 4;
#pragma unroll
        for (int r = 0; r < 4; r++) {
          int m = mrow + r;   // always < M_REAL (overlap tile double-writes)
          outF[(size_t)m * N + d] = acc[i][j][r];
        }
      }
  }
}

// ---- V transpose: v_raw [bh][n][64] -> vT [bh][64][NPAD] patch-aligned ----
__global__ __launch_bounds__(256) void v_transpose_kernel(const bf16* __restrict__ v_raw,
                                                          bf16* __restrict__ vT) {
  __shared__ bf16 tile[64][65];
  int bh = blockIdx.y, c = blockIdx.x;
  int tid = threadIdx.x;
#pragma unroll
  for (int jj = 0; jj < 16; jj++) {
    int idx = tid + jj * 256;
    int i = idx >> 6, e = idx & 63;
    int n = (c == 0) ? i : (64 * c - 60 + i);
    bool ok = (c == 0) ? (i < 4) : (n < NSEQ);
    tile[i][e] = ok ? v_raw[((size_t)bh * NSEQ + n) * HD + e] : (bf16)0.0f;
  }
  __syncthreads();
#pragma unroll
  for (int jj = 0; jj < 16; jj++) {
    int idx = tid + jj * 256;
    int e = idx >> 6, i = idx & 63;
    vT[((size_t)bh * HD + e) * NPAD + 64 * c + i] = tile[i][e];
  }
}

// ---------------- masked flash attention (balanced tiling) ---------------
__global__ __launch_bounds__(256) void attn_kernel(
    const bf16* __restrict__ Q, const bf16* __restrict__ Kb, const bf16* __restrict__ Vt,
    bf16* __restrict__ att, const int* __restrict__ winp) {
  __shared__ __attribute__((aligned(16))) bf16 P_s[4][16][72];
  __shared__ float o_s[4][4][64];
  __shared__ float ml_s[4][2][16];
  const int bh = blockIdx.y, qt = blockIdx.x;
  const int W = winp[0];
  const int tid = threadIdx.x, w = tid >> 6, lane = tid & 63;
  const int l15 = lane & 15, l4 = lane >> 4;
  const size_t qkbase = (size_t)bh * NPAD * HD;
  const size_t vtb = (size_t)bh * HD * NPAD;
  const bool is_spec = (qt == 16);

  const int qrow0 = is_spec ? 0 : (4 + qt * 64 + w * 16);
  bf16x8 aq0 = *(const bf16x8*)&Q[qkbase + (size_t)(qrow0 + l15) * HD + l4 * 8];
  bf16x8 aq1 = *(const bf16x8*)&Q[qkbase + (size_t)(qrow0 + l15) * HD + 32 + l4 * 8];

  float mrow[4], lrow[4];
  f32x4 o[4] = {};
#pragma unroll
  for (int r = 0; r < 4; r++) { mrow[r] = -1e30f; lrow[r] = 0.0f; }

  int p0, pstep, pmax, toff;
  if (is_spec) {
    p0 = w; pstep = 4; pmax = 16; toff = -1;
  } else {
    int ta = ((2 * qt - W + 64) >> 1) - 32;
    int tb = (2 * qt + 1 + W) >> 1;
    ta = ta < 0 ? 0 : ta;
    tb = tb > 15 ? 15 : tb;
    p0 = 0; pstep = 1; pmax = tb - ta + 1; toff = ta - 1;
  }

  for (int p = p0; p <= pmax; p += pstep) {
    const bool sp = (p == 0);
    const int tau = toff + p;
    const int krow0 = sp ? 0 : (4 + tau * 64);
    const int vcol0 = sp ? 0 : (64 + tau * 64);

    f32x4 sacc[4] = {};
#pragma unroll
    for (int kf = 0; kf < 4; kf++) {
      const bf16* kp = &Kb[qkbase + (size_t)(krow0 + kf * 16 + l15) * HD];
      bf16x8 b0 = *(const bf16x8*)(kp + l4 * 8);
      bf16x8 b1 = *(const bf16x8*)(kp + 32 + l4 * 8);
      sacc[kf] = __builtin_amdgcn_mfma_f32_16x16x32_bf16(aq0, b0, sacc[kf], 0, 0, 0);
      sacc[kf] = __builtin_amdgcn_mfma_f32_16x16x32_bf16(aq1, b1, sacc[kf], 0, 0, 0);
    }

    float pvv[4][4];
#pragma unroll
    for (int kf = 0; kf < 4; kf++)
#pragma unroll
      for (int r = 0; r < 4; r++) {
        float s = sacc[kf][r] * 0.125f;
        bool valid;
        if (sp) {
          valid = (kf == 0) && (l15 < 4);
        } else if (is_spec) {
          valid = true;
        } else {
          int p_k = tau * 64 + kf * 16 + l15;
          int p_q = qt * 64 + w * 16 + l4 * 4 + r;
          int dr = (p_q >> 5) - (p_k >> 5); dr = dr < 0 ? -dr : dr;
          int dc = (p_q & 31) - (p_k & 31); dc = dc < 0 ? -dc : dc;
          valid = (dr <= W) && (dc <= W);
        }
        pvv[kf][r] = valid ? s : -1e30f;
      }

#pragma unroll
    for (int r = 0; r < 4; r++) {
      float mx = fmaxf(fmaxf(pvv[0][r], pvv[1][r]), fmaxf(pvv[2][r], pvv[3][r]));
#pragma unroll
      for (int mm = 1; mm < 16; mm <<= 1) mx = fmaxf(mx, __shfl_xor(mx, mm));
      float mnew = fmaxf(mrow[r], mx);
      float scale = __expf(mrow[r] - mnew);
      float rs = 0.0f;
#pragma unroll
      for (int kf = 0; kf < 4; kf++) {
        float pp = __expf(pvv[kf][r] - mnew);
        pvv[kf][r] = pp;
        rs += pp;
      }
#pragma unroll
      for (int mm = 1; mm < 16; mm <<= 1) rs += __shfl_xor(rs, mm);
      lrow[r] = lrow[r] * scale + rs;
      mrow[r] = mnew;
#pragma unroll
      for (int f = 0; f < 4; f++) o[f][r] *= scale;
    }

#pragma unroll
    for (int kf = 0; kf < 4; kf++)
#pragma unroll
      for (int r = 0; r < 4; r++)
        P_s[w][l4 * 4 + r][kf * 16 + l15] = (bf16)pvv[kf][r];

    bf16x8 pa0 = *(const bf16x8*)&P_s[w][l15][l4 * 8];
    bf16x8 pa1 = *(const bf16x8*)&P_s[w][l15][32 + l4 * 8];
#pragma unroll
    for (int f = 0; f < 4; f++) {
      const bf16* vp = &Vt[vtb + (size_t)(f * 16 + l15) * NPAD + vcol0];
      bf16x8 v0 = *(const bf16x8*)(vp + l4 * 8);
      bf16x8 v1 = *(const bf16x8*)(vp + 32 + l4 * 8);
      o[f] = __builtin_amdgcn_mfma_f32_16x16x32_bf16(pa0, v0, o[f], 0, 0, 0);
      o[f] = __builtin_amdgcn_mfma_f32_16x16x32_bf16(pa1, v1, o[f], 0, 0, 0);
    }
  }

  const int b = bh >> 4, h = bh & 15;
  if (!is_spec) {
#pragma unroll
    for (int f = 0; f < 4; f++)
#pragma unroll
      for (int r = 0; r < 4; r++) {
        int n = qrow0 + l4 * 4 + r;
        att[((size_t)(b * NSEQ + n)) * CDIM + h * HD + f * 16 + l15] =
            (bf16)(o[f][r] / lrow[r]);
      }
  } else {
    if (l4 == 0) {
#pragma unroll
      for (int f = 0; f < 4; f++)
#pragma unroll
        for (int r = 0; r < 4; r++) o_s[w][r][f * 16 + l15] = o[f][r];
      if (l15 == 0)
#pragma unroll
        for (int r = 0; r < 4; r++) { ml_s[w][0][r] = mrow[r]; ml_s[w][1][r] = lrow[r]; }
    }
    __syncthreads();
    int row = tid >> 6, dim = tid & 63;
    float M = -1e30f;
#pragma unroll
    for (int ww = 0; ww < 4; ww++) M = fmaxf(M, ml_s[ww][0][row]);
    float L = 0.0f, val = 0.0f;
#pragma unroll
    for (int ww = 0; ww < 4; ww++) {
      float e = __expf(ml_s[ww][0][row] - M);
      L += e * ml_s[ww][1][row];
      val += e * o_s[ww][row][dim];
    }
    att[((size_t)(b * NSEQ + row)) * CDIM + h * HD + dim] = (bf16)(val / L);
  }
}

// ------------------------------------------------------------------------
extern "C" void kernel_launch(void* const* d_in, const int* in_sizes, int n_in,
                              void* d_out, int out_size, void* d_ws, size_t ws_size,
                              hipStream_t stream) {
  const float* hidden = (const float*)d_in[0];
  const float* cosb = (const float*)d_in[1];
  const float* sinb = (const float*)d_in[2];
  const float* qkv_w = (const float*)d_in[3];
  const float* out_w = (const float*)d_in[4];
  const float* norm_q_w = (const float*)d_in[5];
  const float* norm_k_w = (const float*)d_in[6];
  const int* win = (const int*)d_in[7];
  float* out = (float*)d_out;

  char* ws = (char*)d_ws;
  size_t off = 0;
  auto alloc = [&](size_t bytes) {
    char* p = ws + off;
    off += (bytes + 255) & ~(size_t)255;
    return p;
  };
  bf16* A_bf  = (bf16*)alloc((size_t)M_REAL * CDIM * 2);
  bf16* W1    = (bf16*)alloc((size_t)3 * CDIM * CDIM * 2);
  bf16* W2    = (bf16*)alloc((size_t)CDIM * CDIM * 2);
  bf16* v_raw = (bf16*)alloc((size_t)BHN * NSEQ * HD * 2);
  bf16* q_bf  = (bf16*)alloc((size_t)BHN * NPAD * HD * 2);
  bf16* k_bf  = (bf16*)alloc((size_t)BHN * NPAD * HD * 2);
  bf16* vT    = (bf16*)alloc((size_t)BHN * HD * NPAD * 2);
  bf16* att   = (bf16*)alloc((size_t)M_REAL * CDIM * 2);
  (void)ws_size; (void)in_sizes; (void)n_in; (void)out_size;

  cast3_kernel<<<2048, 256, 0, stream>>>(
      hidden, A_bf, (long)M_REAL * CDIM,
      qkv_w, W1, (long)3 * CDIM * CDIM,
      out_w, W2, (long)CDIM * CDIM);

  // GEMM1 (exact R9): 8 XCD x 3 n-strips x 33 m-tiles = 792 blocks, BN=128;
  // 0.75MB W1 strip/XCD L2-pinned.
  gemm_bf16_kernel<0, 3, 128><<<792, 256, 0, stream>>>(
      A_bf, W1, q_bf, k_bf, v_raw, nullptr, cosb, sinb, norm_q_w, norm_k_w);
  v_transpose_kernel<<<dim3(17, 64), 256, 0, stream>>>(v_raw, vT);
  attn_kernel<<<dim3(17, 64), 256, 0, stream>>>(q_bf, k_bf, vT, att, win);
  // GEMM2: BN=64 -> 8 XCD x 2 n-strips x 33 m-tiles = 528 blocks (2.06/CU);
  // 0.25MB W2 strip/XCD L2-pinned.
  gemm_bf16_kernel<1, 2, 64><<<528, 256, 0, stream>>>(
      att, W2, nullptr, nullptr, nullptr, out, nullptr, nullptr, nullptr, nullptr);
}